// Round 3
// baseline (646.306 us; speedup 1.0000x reference)
//
#include <hip/hip_runtime.h>
#include <math.h>

#define N 1024
#define C 384
#define H 12
#define CH 32
#define DP 128
#define HP 144
#define MT 64   // m-tile (keys per tile)
#define RW 8    // q-rows per wave
#define QBL 32  // q-rows per block
#define SCALING 0.17677669529663687f
#define LN_EPS 1e-5f

// ---------------- K1: fused projections GEMM ----------------
__global__ __launch_bounds__(256) void k_qkv(
    const float* __restrict__ single,
    const float* __restrict__ Wq, const float* __restrict__ bq,
    const float* __restrict__ Wk, const float* __restrict__ bk,
    const float* __restrict__ Wv, const float* __restrict__ bv,
    const float* __restrict__ Wpq, const float* __restrict__ bpq,
    const float* __restrict__ Wpk, const float* __restrict__ bpk,
    float* __restrict__ q, float* __restrict__ kT, float* __restrict__ v,
    float* __restrict__ qp, float* __restrict__ kp)
{
  __shared__ __align__(16) float A_s[64 * 33];
  __shared__ __align__(16) float B_s[32 * 48];
  int t = threadIdx.x;
  int nt = blockIdx.x, mt = blockIdx.y;
  int m0 = mt * 64;
  const float* W; const float* bias; int ld, kind, cb;
  if (nt < 8)       { W = Wq;  bias = bq;  ld = C;  cb = nt * 48;        kind = 0; }
  else if (nt < 16) { W = Wk;  bias = bk;  ld = C;  cb = (nt - 8) * 48;  kind = 1; }
  else if (nt < 24) { W = Wv;  bias = bv;  ld = C;  cb = (nt - 16) * 48; kind = 2; }
  else if (nt < 27) { W = Wpq; bias = bpq; ld = HP; cb = (nt - 24) * 48; kind = 3; }
  else              { W = Wpk; bias = bpk; ld = HP; cb = (nt - 27) * 48; kind = 4; }
  int tr = t >> 4, tc = t & 15;
  float acc[4][3] = {};
  for (int k0 = 0; k0 < C; k0 += 32) {
    if (k0) __syncthreads();
    #pragma unroll
    for (int i = 0; i < 8; i++) {
      int fi = i * 256 + t; int row = fi >> 5, col = fi & 31;
      A_s[row * 33 + col] = single[(m0 + row) * C + k0 + col];
    }
    #pragma unroll
    for (int i = 0; i < 6; i++) {
      int fi = i * 256 + t; int row = fi / 48, col = fi % 48;
      B_s[row * 48 + col] = W[(k0 + row) * ld + cb + col];
    }
    __syncthreads();
    #pragma unroll
    for (int k = 0; k < 32; k++) {
      float a[4], b[3];
      #pragma unroll
      for (int r = 0; r < 4; r++) a[r] = A_s[(tr * 4 + r) * 33 + k];
      #pragma unroll
      for (int c = 0; c < 3; c++) b[c] = B_s[k * 48 + tc * 3 + c];
      #pragma unroll
      for (int r = 0; r < 4; r++)
        #pragma unroll
        for (int c = 0; c < 3; c++) acc[r][c] = fmaf(a[r], b[c], acc[r][c]);
    }
  }
  #pragma unroll
  for (int c = 0; c < 3; c++) {
    int col = cb + tc * 3 + c;
    float bb = bias[col];
    #pragma unroll
    for (int r = 0; r < 4; r++) {
      int row = m0 + tr * 4 + r;
      float val = acc[r][c] + bb;
      if (kind == 0)      q[row * C + col] = val;
      else if (kind == 1) kT[col * N + row] = val;
      else if (kind == 2) v[row * C + col] = val;
      else if (kind == 3) qp[row * HP + col] = val;
      else                kp[row * HP + col] = val;
    }
  }
}

// ---------------- K1b: rotate points, sq/sk sums ----------------
__global__ __launch_bounds__(256) void k_rot(
    const float* __restrict__ qp, const float* __restrict__ kp,
    const float* __restrict__ rot,
    float* __restrict__ qg, float* __restrict__ kgT,
    float* __restrict__ sq, float* __restrict__ skT)
{
  __shared__ __align__(16) float qp_s[HP], kp_s[HP], rot_s[9], q2_s[HP], k2_s[HP];
  int n = blockIdx.x, t = threadIdx.x;
  if (t < HP) { qp_s[t] = qp[n * HP + t]; kp_s[t] = kp[n * HP + t]; }
  if (t < 9)  rot_s[t] = rot[n * 9 + t];
  __syncthreads();
  if (t < HP) {
    int h = t / 12, r12 = t % 12, y = r12 >> 2, p = r12 & 3;
    float qgv = rot_s[y*3] * qp_s[h*12 + p] + rot_s[y*3+1] * qp_s[h*12 + 4 + p]
              + rot_s[y*3+2] * qp_s[h*12 + 8 + p];
    float kgv = rot_s[y*3] * kp_s[h*12 + p] + rot_s[y*3+1] * kp_s[h*12 + 4 + p]
              + rot_s[y*3+2] * kp_s[h*12 + 8 + p];
    qg[n * HP + t] = qgv; kgT[t * N + n] = kgv;
    q2_s[t] = qgv * qgv; k2_s[t] = kgv * kgv;
  }
  __syncthreads();
  if (t < H) {
    float s1 = 0.f, s2 = 0.f;
    #pragma unroll
    for (int e = 0; e < 12; e++) { s1 += q2_s[t * 12 + e]; s2 += k2_s[t * 12 + e]; }
    sq[n * H + t] = s1; skT[t * N + n] = s2;
  }
}

// ---------------- K2: pair bias GEMM [N*N,128] @ [128,12] ----------------
// reg-prefetch double-buffer: issue chunk c+1 loads before computing chunk c.
__global__ __launch_bounds__(256) void k_pb(
    const float4* __restrict__ pair4, const float* __restrict__ Wp,
    const float* __restrict__ bp, float* __restrict__ pb)
{
  __shared__ __align__(16) float4 pair_s[256 * 8];
  __shared__ __align__(16) float wp_s[12 * 128];
  int t = threadIdx.x;
  long r0 = (long)blockIdx.x * 256;
  #pragma unroll
  for (int i = 0; i < 6; i++) {
    int fi = i * 256 + t; int h = fi >> 7, d = fi & 127;
    wp_s[h * 128 + d] = Wp[d * 12 + h];
  }
  float4 pre[8];
  #pragma unroll
  for (int i = 0; i < 8; i++) {
    int fi = i * 256 + t; int row = fi >> 3, q4 = fi & 7;
    pre[i] = pair4[(r0 + row) * 32 + q4];
  }
  #pragma unroll
  for (int i = 0; i < 8; i++) {
    int fi = i * 256 + t; int row = fi >> 3, q4 = fi & 7;
    pair_s[row * 8 + (q4 ^ (row & 7))] = pre[i];
  }
  __syncthreads();
  float acc[12] = {};
  const float4* wp4 = (const float4*)wp_s;
  for (int chunk = 0; chunk < 4; chunk++) {
    if (chunk < 3) {
      #pragma unroll
      for (int i = 0; i < 8; i++) {
        int fi = i * 256 + t; int row = fi >> 3, q4 = fi & 7;
        pre[i] = pair4[(r0 + row) * 32 + (chunk + 1) * 8 + q4];
      }
    }
    #pragma unroll
    for (int d4 = 0; d4 < 8; d4++) {
      float4 a = pair_s[t * 8 + (d4 ^ (t & 7))];
      #pragma unroll
      for (int h = 0; h < 12; h++) {
        float4 w = wp4[h * 32 + chunk * 8 + d4];
        acc[h] = fmaf(a.x, w.x, acc[h]);
        acc[h] = fmaf(a.y, w.y, acc[h]);
        acc[h] = fmaf(a.z, w.z, acc[h]);
        acc[h] = fmaf(a.w, w.w, acc[h]);
      }
    }
    __syncthreads();
    if (chunk < 3) {
      #pragma unroll
      for (int i = 0; i < 8; i++) {
        int fi = i * 256 + t; int row = fi >> 3, q4 = fi & 7;
        pair_s[row * 8 + (q4 ^ (row & 7))] = pre[i];
      }
      __syncthreads();
    }
  }
  #pragma unroll
  for (int h = 0; h < 12; h++)
    pb[(long)h * (N * (long)N) + r0 + t] = acc[h] + bp[h];
}

// ---------------- K3: flash attention v3 ----------------
// One block = (1 head, 32 q-rows); 4 waves x 8 rows. Per m-tile of 64 keys,
// stage k/v/kg in LDS once (amortized over 32 rows), prefetch next tile +
// next pb rows into registers before computing current tile (T14 pattern).
// blockIdx remap puts ~2 heads per XCD -> per-XCD hot set ~600 KB (L2-hot).
__global__ __launch_bounds__(256) void k_attn(
    const float* __restrict__ q, const float* __restrict__ kT,
    const float* __restrict__ v, const float* __restrict__ qg,
    const float* __restrict__ kgT, const float* __restrict__ sq,
    const float* __restrict__ skT, const float* __restrict__ pb,
    float* __restrict__ wt)
{
  __shared__ __align__(16) float k_s[32][MT];    // [c][m]
  __shared__ __align__(16) float v_s[MT][32];    // [m][c]
  __shared__ __align__(16) float kg_s[12][MT];   // [e][m]
  __shared__ __align__(16) float q_s[QBL][32];
  __shared__ __align__(16) float qg_s[QBL][12];
  __shared__ __align__(16) float sq_s[QBL];
  __shared__ __align__(16) float p_s[4][RW][MT];

  int t = threadIdx.x;
  int bid = blockIdx.x;
  int s = (bid & 7) * 48 + (bid >> 3);   // sort blocks by head across XCDs
  int h = s >> 5, qb = s & 31;
  int q0 = qb * QBL;
  int w = t >> 6, lane = t & 63;
  long pbbase = (long)h * (N * (long)N);

  // stage q block once
  for (int idx = t; idx < QBL * 8; idx += 256) {
    int r = idx >> 3, c4 = idx & 7;
    *(float4*)&q_s[r][c4 * 4] = *(const float4*)&q[(q0 + r) * C + h * 32 + c4 * 4];
  }
  for (int idx = t; idx < QBL * 3; idx += 256) {
    int r = idx / 3, e4 = idx % 3;
    *(float4*)&qg_s[r][e4 * 4] = *(const float4*)&qg[(q0 + r) * HP + h * 12 + e4 * 4];
  }
  if (t < QBL) sq_s[t] = sq[(q0 + t) * H + h];

  int c0 = t >> 4, m4 = t & 15;          // k/kg job coords
  int mr0 = t >> 3, c4v = t & 7;         // v job coords
  float4 pre[5];
  float pb_cur[RW], pb_nxt[RW];

#define STAGE_LOAD(M0) \
  { pre[0] = *(const float4*)&kT[(h * 32 + c0) * N + (M0) + m4 * 4]; \
    pre[1] = *(const float4*)&kT[(h * 32 + 16 + c0) * N + (M0) + m4 * 4]; \
    pre[2] = *(const float4*)&v[((M0) + mr0) * C + h * 32 + c4v * 4]; \
    pre[3] = *(const float4*)&v[((M0) + mr0 + 32) * C + h * 32 + c4v * 4]; \
    if (t < 192) pre[4] = *(const float4*)&kgT[(h * 12 + c0) * N + (M0) + m4 * 4]; }

#define STAGE_WRITE() \
  { *(float4*)&k_s[c0][m4 * 4] = pre[0]; \
    *(float4*)&k_s[16 + c0][m4 * 4] = pre[1]; \
    *(float4*)&v_s[mr0][c4v * 4] = pre[2]; \
    *(float4*)&v_s[mr0 + 32][c4v * 4] = pre[3]; \
    if (t < 192) *(float4*)&kg_s[c0][m4 * 4] = pre[4]; }

  STAGE_LOAD(0);
  #pragma unroll
  for (int r = 0; r < RW; r++)
    pb_cur[r] = pb[pbbase + (long)(q0 + w * RW + r) * N + lane];
  STAGE_WRITE();
  __syncthreads();

  float mrun[RW], lrun[RW] = {}, o[RW] = {};
  #pragma unroll
  for (int r = 0; r < RW; r++) mrun[r] = -INFINITY;

  for (int tile = 0; tile < 16; tile++) {
    int m0 = tile * MT;
    if (tile < 15) {
      STAGE_LOAD(m0 + MT);
      #pragma unroll
      for (int r = 0; r < RW; r++)
        pb_nxt[r] = pb[pbbase + (long)(q0 + w * RW + r) * N + m0 + MT + lane];
    }
    // ---- QK^T + point logits + online softmax (lanes = m) ----
    float kr[32], kgr[12];
    #pragma unroll
    for (int c = 0; c < 32; c++) kr[c] = k_s[c][lane];
    #pragma unroll
    for (int e = 0; e < 12; e++) kgr[e] = kg_s[e][lane];
    float skv = skT[h * N + m0 + lane];
    float sc[RW];
    #pragma unroll
    for (int r = 0; r < RW; r++) {
      int row = w * RW + r;
      float a0 = 0.f, a1 = 0.f, a2 = 0.f, a3 = 0.f;
      const float4* q4p = (const float4*)q_s[row];
      #pragma unroll
      for (int c4 = 0; c4 < 8; c4++) {
        float4 qv = q4p[c4];
        a0 = fmaf(qv.x, kr[c4 * 4],     a0);
        a1 = fmaf(qv.y, kr[c4 * 4 + 1], a1);
        a2 = fmaf(qv.z, kr[c4 * 4 + 2], a2);
        a3 = fmaf(qv.w, kr[c4 * 4 + 3], a3);
      }
      float b0 = 0.f, b1 = 0.f, b2 = 0.f, b3 = 0.f;
      const float4* qg4p = (const float4*)qg_s[row];
      #pragma unroll
      for (int e4 = 0; e4 < 3; e4++) {
        float4 qv = qg4p[e4];
        b0 = fmaf(qv.x, kgr[e4 * 4],     b0);
        b1 = fmaf(qv.y, kgr[e4 * 4 + 1], b1);
        b2 = fmaf(qv.z, kgr[e4 * 4 + 2], b2);
        b3 = fmaf(qv.w, kgr[e4 * 4 + 3], b3);
      }
      float Lq = (a0 + a1) + (a2 + a3);
      float Lp = (b0 + b1) + (b2 + b3);
      float L = Lq * SCALING + pb_cur[r]
              - 0.5f * SCALING * (sq_s[row] + skv - 2.0f * Lp);
      float tmax = L;
      #pragma unroll
      for (int off = 32; off; off >>= 1) tmax = fmaxf(tmax, __shfl_xor(tmax, off));
      float mnew = fmaxf(mrun[r], tmax);
      float p = __expf(L - mnew);
      float ts = p;
      #pragma unroll
      for (int off = 32; off; off >>= 1) ts += __shfl_xor(ts, off);
      sc[r] = __expf(mrun[r] - mnew);
      lrun[r] = lrun[r] * sc[r] + ts;
      mrun[r] = mnew;
      p_s[w][r][lane] = p;     // wave-private row
    }
    // ---- AV (lanes = (c, m-half)) ----
    {
      int cc = lane & 31, seg = lane >> 5;
      float vr[32];
      #pragma unroll
      for (int jj = 0; jj < 32; jj++) vr[jj] = v_s[seg * 32 + jj][cc];
      #pragma unroll
      for (int r = 0; r < RW; r++) {
        float ax = o[r] * sc[r], ay = 0.f, az = 0.f, aw = 0.f;
        const float4* p4 = (const float4*)&p_s[w][r][seg * 32];
        #pragma unroll
        for (int j4 = 0; j4 < 8; j4++) {
          float4 pv = p4[j4];
          ax = fmaf(pv.x, vr[j4 * 4],     ax);
          ay = fmaf(pv.y, vr[j4 * 4 + 1], ay);
          az = fmaf(pv.z, vr[j4 * 4 + 2], az);
          aw = fmaf(pv.w, vr[j4 * 4 + 3], aw);
        }
        o[r] = (ax + ay) + (az + aw);
      }
    }
    __syncthreads();
    if (tile < 15) {
      STAGE_WRITE();
      #pragma unroll
      for (int r = 0; r < RW; r++) pb_cur[r] = pb_nxt[r];
    }
    __syncthreads();
  }
  #pragma unroll
  for (int r = 0; r < RW; r++) {
    float ov = o[r] + __shfl_xor(o[r], 32);
    if (lane < 32) wt[(q0 + w * RW + r) * C + h * 32 + lane] = ov / lrun[r];
  }
#undef STAGE_LOAD
#undef STAGE_WRITE
}

// ---------------- K4: output GEMM + residual + LayerNorm ----------------
__global__ __launch_bounds__(384) void k_out(
    const float* __restrict__ wt, const float* __restrict__ Wo,
    const float* __restrict__ bo, const float* __restrict__ single,
    const float* __restrict__ gamma, const float* __restrict__ beta,
    float* __restrict__ out)
{
  __shared__ __align__(16) float wt_s[4 * C];
  __shared__ __align__(16) float red[4][2][6];
  int t = threadIdx.x, n0 = blockIdx.x * 4;
  for (int idx = t; idx < 4 * C; idx += 384) wt_s[idx] = wt[n0 * C + idx];
  __syncthreads();
  float acc[4] = {};
  for (int ck = 0; ck < C; ck++) {
    float w = Wo[ck * C + t];
    #pragma unroll
    for (int i = 0; i < 4; i++) acc[i] = fmaf(wt_s[i * C + ck], w, acc[i]);
  }
  float x[4], bov = bo[t];
  #pragma unroll
  for (int i = 0; i < 4; i++) x[i] = single[(n0 + i) * C + t] + acc[i] + bov;
  int wid = t >> 6, lane = t & 63;
  #pragma unroll
  for (int i = 0; i < 4; i++) {
    float s = x[i], s2 = x[i] * x[i];
    #pragma unroll
    for (int off = 32; off; off >>= 1) { s += __shfl_xor(s, off); s2 += __shfl_xor(s2, off); }
    if (lane == 0) { red[i][0][wid] = s; red[i][1][wid] = s2; }
  }
  __syncthreads();
  float gv = gamma[t], bv = beta[t];
  #pragma unroll
  for (int i = 0; i < 4; i++) {
    float S = 0.f, S2 = 0.f;
    #pragma unroll
    for (int w = 0; w < 6; w++) { S += red[i][0][w]; S2 += red[i][1][w]; }
    float mu = S * (1.0f / C);
    float var = S2 * (1.0f / C) - mu * mu;
    out[(n0 + i) * C + t] = (x[i] - mu) * rsqrtf(var + LN_EPS) * gv + bv;
  }
}

extern "C" void kernel_launch(void* const* d_in, const int* in_sizes, int n_in,
                              void* d_out, int out_size, void* d_ws, size_t ws_size,
                              hipStream_t stream) {
  const float* single = (const float*)d_in[0];
  const float* pair   = (const float*)d_in[1];
  const float* rot    = (const float*)d_in[2];
  const float* Wq  = (const float*)d_in[4];  const float* bq  = (const float*)d_in[5];
  const float* Wk  = (const float*)d_in[6];  const float* bk  = (const float*)d_in[7];
  const float* Wv  = (const float*)d_in[8];  const float* bv  = (const float*)d_in[9];
  const float* Wp  = (const float*)d_in[10]; const float* bp  = (const float*)d_in[11];
  const float* Wpq = (const float*)d_in[12]; const float* bpq = (const float*)d_in[13];
  const float* Wpk = (const float*)d_in[14]; const float* bpk = (const float*)d_in[15];
  const float* Wo  = (const float*)d_in[16]; const float* bo  = (const float*)d_in[17];
  const float* gamma = (const float*)d_in[18]; const float* beta = (const float*)d_in[19];

  float* ws  = (float*)d_ws;
  float* pb  = ws;                           // [12][1024*1024]
  float* q   = pb + 12L * N * N;             // [N][C]
  float* kT  = q   + N * C;                  // [C][N]
  float* v   = kT  + N * C;                  // [N][C]
  float* qp  = v   + N * C;                  // [N][144]
  float* kp  = qp  + N * HP;                 // [N][144]
  float* qg  = kp  + N * HP;                 // [N][144]
  float* kgT = qg  + N * HP;                 // [144][N]
  float* sq  = kgT + N * HP;                 // [N][12]
  float* skT = sq  + N * H;                  // [12][N]
  float* wt  = skT + N * H;                  // [N][C]

  k_qkv<<<dim3(30, 16), 256, 0, stream>>>(single, Wq, bq, Wk, bk, Wv, bv,
                                          Wpq, bpq, Wpk, bpk, q, kT, v, qp, kp);
  k_rot<<<N, 256, 0, stream>>>(qp, kp, rot, qg, kgT, sq, skT);
  k_pb<<<4096, 256, 0, stream>>>((const float4*)pair, Wp, bp, pb);
  k_attn<<<384, 256, 0, stream>>>(q, kT, v, qg, kgT, sq, skT, pb, wt);
  k_out<<<256, 384, 0, stream>>>(wt, Wo, bo, single, gamma, beta, (float*)d_out);
}

// Round 4
// 445.464 us; speedup vs baseline: 1.4509x; 1.4509x over previous
//
#include <hip/hip_runtime.h>
#include <math.h>

#define N 1024
#define C 384
#define H 12
#define CH 32
#define DP 128
#define HP 144
#define MT 64   // m-tile (keys per tile)
#define RW 8    // q-rows per wave
#define QBL 32  // q-rows per block
#define SCALING 0.17677669529663687f
#define LN_EPS 1e-5f

// ---------------- K1: fused projections GEMM ----------------
__global__ __launch_bounds__(256) void k_qkv(
    const float* __restrict__ single,
    const float* __restrict__ Wq, const float* __restrict__ bq,
    const float* __restrict__ Wk, const float* __restrict__ bk,
    const float* __restrict__ Wv, const float* __restrict__ bv,
    const float* __restrict__ Wpq, const float* __restrict__ bpq,
    const float* __restrict__ Wpk, const float* __restrict__ bpk,
    float* __restrict__ q, float* __restrict__ kT, float* __restrict__ v,
    float* __restrict__ qp, float* __restrict__ kp)
{
  __shared__ __align__(16) float A_s[64 * 33];
  __shared__ __align__(16) float B_s[32 * 48];
  int t = threadIdx.x;
  int nt = blockIdx.x, mt = blockIdx.y;
  int m0 = mt * 64;
  const float* W; const float* bias; int ld, kind, cb;
  if (nt < 8)       { W = Wq;  bias = bq;  ld = C;  cb = nt * 48;        kind = 0; }
  else if (nt < 16) { W = Wk;  bias = bk;  ld = C;  cb = (nt - 8) * 48;  kind = 1; }
  else if (nt < 24) { W = Wv;  bias = bv;  ld = C;  cb = (nt - 16) * 48; kind = 2; }
  else if (nt < 27) { W = Wpq; bias = bpq; ld = HP; cb = (nt - 24) * 48; kind = 3; }
  else              { W = Wpk; bias = bpk; ld = HP; cb = (nt - 27) * 48; kind = 4; }
  int tr = t >> 4, tc = t & 15;
  float acc[4][3] = {};
  for (int k0 = 0; k0 < C; k0 += 32) {
    if (k0) __syncthreads();
    #pragma unroll
    for (int i = 0; i < 8; i++) {
      int fi = i * 256 + t; int row = fi >> 5, col = fi & 31;
      A_s[row * 33 + col] = single[(m0 + row) * C + k0 + col];
    }
    #pragma unroll
    for (int i = 0; i < 6; i++) {
      int fi = i * 256 + t; int row = fi / 48, col = fi % 48;
      B_s[row * 48 + col] = W[(k0 + row) * ld + cb + col];
    }
    __syncthreads();
    #pragma unroll
    for (int k = 0; k < 32; k++) {
      float a[4], b[3];
      #pragma unroll
      for (int r = 0; r < 4; r++) a[r] = A_s[(tr * 4 + r) * 33 + k];
      #pragma unroll
      for (int c = 0; c < 3; c++) b[c] = B_s[k * 48 + tc * 3 + c];
      #pragma unroll
      for (int r = 0; r < 4; r++)
        #pragma unroll
        for (int c = 0; c < 3; c++) acc[r][c] = fmaf(a[r], b[c], acc[r][c]);
    }
  }
  #pragma unroll
  for (int c = 0; c < 3; c++) {
    int col = cb + tc * 3 + c;
    float bb = bias[col];
    #pragma unroll
    for (int r = 0; r < 4; r++) {
      int row = m0 + tr * 4 + r;
      float val = acc[r][c] + bb;
      if (kind == 0)      q[row * C + col] = val;
      else if (kind == 1) kT[col * N + row] = val;
      else if (kind == 2) v[row * C + col] = val;
      else if (kind == 3) qp[row * HP + col] = val;
      else                kp[row * HP + col] = val;
    }
  }
}

// ---------------- K1b: rotate points, sq/sk sums ----------------
__global__ __launch_bounds__(256) void k_rot(
    const float* __restrict__ qp, const float* __restrict__ kp,
    const float* __restrict__ rot,
    float* __restrict__ qg, float* __restrict__ kgT,
    float* __restrict__ sq, float* __restrict__ skT)
{
  __shared__ __align__(16) float qp_s[HP], kp_s[HP], rot_s[9], q2_s[HP], k2_s[HP];
  int n = blockIdx.x, t = threadIdx.x;
  if (t < HP) { qp_s[t] = qp[n * HP + t]; kp_s[t] = kp[n * HP + t]; }
  if (t < 9)  rot_s[t] = rot[n * 9 + t];
  __syncthreads();
  if (t < HP) {
    int h = t / 12, r12 = t % 12, y = r12 >> 2, p = r12 & 3;
    float qgv = rot_s[y*3] * qp_s[h*12 + p] + rot_s[y*3+1] * qp_s[h*12 + 4 + p]
              + rot_s[y*3+2] * qp_s[h*12 + 8 + p];
    float kgv = rot_s[y*3] * kp_s[h*12 + p] + rot_s[y*3+1] * kp_s[h*12 + 4 + p]
              + rot_s[y*3+2] * kp_s[h*12 + 8 + p];
    qg[n * HP + t] = qgv; kgT[t * N + n] = kgv;
    q2_s[t] = qgv * qgv; k2_s[t] = kgv * kgv;
  }
  __syncthreads();
  if (t < H) {
    float s1 = 0.f, s2 = 0.f;
    #pragma unroll
    for (int e = 0; e < 12; e++) { s1 += q2_s[t * 12 + e]; s2 += k2_s[t * 12 + e]; }
    sq[n * H + t] = s1; skT[t * N + n] = s2;
  }
}

// ---------------- K2: pair bias GEMM [N*N,128] @ [128,12] ----------------
// Barrier-free streaming: 1 thread = 1 output row. 32 sequential float4
// loads of pair row (lane stride 512B; every 64B line fully consumed),
// Wp broadcast from 6KB LDS (conflict-free), 12 VGPR accumulators,
// coalesced stores to [H][N*N]. No staging, no barriers in the hot loop.
__global__ __launch_bounds__(256) void k_pb(
    const float4* __restrict__ pair4, const float* __restrict__ Wp,
    const float* __restrict__ bp, float* __restrict__ pb)
{
  __shared__ __align__(16) float wp_s[12 * 128];   // [h][d], transposed
  int t = threadIdx.x;
  #pragma unroll
  for (int i = 0; i < 6; i++) {
    int fi = i * 256 + t; int h = fi >> 7, d = fi & 127;
    wp_s[h * 128 + d] = Wp[d * 12 + h];
  }
  __syncthreads();
  long row = (long)blockIdx.x * 256 + t;
  const float4* rp = pair4 + row * 32;
  const float4* w4 = (const float4*)wp_s;          // [h][32]
  float acc[12] = {};
  #pragma unroll 4
  for (int d4 = 0; d4 < 32; d4++) {
    float4 a = rp[d4];
    #pragma unroll
    for (int h = 0; h < 12; h++) {
      float4 w = w4[h * 32 + d4];
      acc[h] = fmaf(a.x, w.x, acc[h]);
      acc[h] = fmaf(a.y, w.y, acc[h]);
      acc[h] = fmaf(a.z, w.z, acc[h]);
      acc[h] = fmaf(a.w, w.w, acc[h]);
    }
  }
  #pragma unroll
  for (int h = 0; h < 12; h++)
    pb[(long)h * (N * (long)N) + row] = acc[h] + bp[h];
}

// ---------------- K3: flash attention v3 (unchanged this round) ----------------
__global__ __launch_bounds__(256) void k_attn(
    const float* __restrict__ q, const float* __restrict__ kT,
    const float* __restrict__ v, const float* __restrict__ qg,
    const float* __restrict__ kgT, const float* __restrict__ sq,
    const float* __restrict__ skT, const float* __restrict__ pb,
    float* __restrict__ wt)
{
  __shared__ __align__(16) float k_s[32][MT];
  __shared__ __align__(16) float v_s[MT][32];
  __shared__ __align__(16) float kg_s[12][MT];
  __shared__ __align__(16) float q_s[QBL][32];
  __shared__ __align__(16) float qg_s[QBL][12];
  __shared__ __align__(16) float sq_s[QBL];
  __shared__ __align__(16) float p_s[4][RW][MT];

  int t = threadIdx.x;
  int bid = blockIdx.x;
  int s = (bid & 7) * 48 + (bid >> 3);
  int h = s >> 5, qb = s & 31;
  int q0 = qb * QBL;
  int w = t >> 6, lane = t & 63;
  long pbbase = (long)h * (N * (long)N);

  for (int idx = t; idx < QBL * 8; idx += 256) {
    int r = idx >> 3, c4 = idx & 7;
    *(float4*)&q_s[r][c4 * 4] = *(const float4*)&q[(q0 + r) * C + h * 32 + c4 * 4];
  }
  for (int idx = t; idx < QBL * 3; idx += 256) {
    int r = idx / 3, e4 = idx % 3;
    *(float4*)&qg_s[r][e4 * 4] = *(const float4*)&qg[(q0 + r) * HP + h * 12 + e4 * 4];
  }
  if (t < QBL) sq_s[t] = sq[(q0 + t) * H + h];

  int c0 = t >> 4, m4 = t & 15;
  int mr0 = t >> 3, c4v = t & 7;
  float4 pre[5];
  float pb_cur[RW], pb_nxt[RW];

#define STAGE_LOAD(M0) \
  { pre[0] = *(const float4*)&kT[(h * 32 + c0) * N + (M0) + m4 * 4]; \
    pre[1] = *(const float4*)&kT[(h * 32 + 16 + c0) * N + (M0) + m4 * 4]; \
    pre[2] = *(const float4*)&v[((M0) + mr0) * C + h * 32 + c4v * 4]; \
    pre[3] = *(const float4*)&v[((M0) + mr0 + 32) * C + h * 32 + c4v * 4]; \
    if (t < 192) pre[4] = *(const float4*)&kgT[(h * 12 + c0) * N + (M0) + m4 * 4]; }

#define STAGE_WRITE() \
  { *(float4*)&k_s[c0][m4 * 4] = pre[0]; \
    *(float4*)&k_s[16 + c0][m4 * 4] = pre[1]; \
    *(float4*)&v_s[mr0][c4v * 4] = pre[2]; \
    *(float4*)&v_s[mr0 + 32][c4v * 4] = pre[3]; \
    if (t < 192) *(float4*)&kg_s[c0][m4 * 4] = pre[4]; }

  STAGE_LOAD(0);
  #pragma unroll
  for (int r = 0; r < RW; r++)
    pb_cur[r] = pb[pbbase + (long)(q0 + w * RW + r) * N + lane];
  STAGE_WRITE();
  __syncthreads();

  float mrun[RW], lrun[RW] = {}, o[RW] = {};
  #pragma unroll
  for (int r = 0; r < RW; r++) mrun[r] = -INFINITY;

  for (int tile = 0; tile < 16; tile++) {
    int m0 = tile * MT;
    if (tile < 15) {
      STAGE_LOAD(m0 + MT);
      #pragma unroll
      for (int r = 0; r < RW; r++)
        pb_nxt[r] = pb[pbbase + (long)(q0 + w * RW + r) * N + m0 + MT + lane];
    }
    float kr[32], kgr[12];
    #pragma unroll
    for (int c = 0; c < 32; c++) kr[c] = k_s[c][lane];
    #pragma unroll
    for (int e = 0; e < 12; e++) kgr[e] = kg_s[e][lane];
    float skv = skT[h * N + m0 + lane];
    float sc[RW];
    #pragma unroll
    for (int r = 0; r < RW; r++) {
      int row = w * RW + r;
      float a0 = 0.f, a1 = 0.f, a2 = 0.f, a3 = 0.f;
      const float4* q4p = (const float4*)q_s[row];
      #pragma unroll
      for (int c4 = 0; c4 < 8; c4++) {
        float4 qv = q4p[c4];
        a0 = fmaf(qv.x, kr[c4 * 4],     a0);
        a1 = fmaf(qv.y, kr[c4 * 4 + 1], a1);
        a2 = fmaf(qv.z, kr[c4 * 4 + 2], a2);
        a3 = fmaf(qv.w, kr[c4 * 4 + 3], a3);
      }
      float b0 = 0.f, b1 = 0.f, b2 = 0.f, b3 = 0.f;
      const float4* qg4p = (const float4*)qg_s[row];
      #pragma unroll
      for (int e4 = 0; e4 < 3; e4++) {
        float4 qv = qg4p[e4];
        b0 = fmaf(qv.x, kgr[e4 * 4],     b0);
        b1 = fmaf(qv.y, kgr[e4 * 4 + 1], b1);
        b2 = fmaf(qv.z, kgr[e4 * 4 + 2], b2);
        b3 = fmaf(qv.w, kgr[e4 * 4 + 3], b3);
      }
      float Lq = (a0 + a1) + (a2 + a3);
      float Lp = (b0 + b1) + (b2 + b3);
      float L = Lq * SCALING + pb_cur[r]
              - 0.5f * SCALING * (sq_s[row] + skv - 2.0f * Lp);
      float tmax = L;
      #pragma unroll
      for (int off = 32; off; off >>= 1) tmax = fmaxf(tmax, __shfl_xor(tmax, off));
      float mnew = fmaxf(mrun[r], tmax);
      float p = __expf(L - mnew);
      float ts = p;
      #pragma unroll
      for (int off = 32; off; off >>= 1) ts += __shfl_xor(ts, off);
      sc[r] = __expf(mrun[r] - mnew);
      lrun[r] = lrun[r] * sc[r] + ts;
      mrun[r] = mnew;
      p_s[w][r][lane] = p;
    }
    {
      int cc = lane & 31, seg = lane >> 5;
      float vr[32];
      #pragma unroll
      for (int jj = 0; jj < 32; jj++) vr[jj] = v_s[seg * 32 + jj][cc];
      #pragma unroll
      for (int r = 0; r < RW; r++) {
        float ax = o[r] * sc[r], ay = 0.f, az = 0.f, aw = 0.f;
        const float4* p4 = (const float4*)&p_s[w][r][seg * 32];
        #pragma unroll
        for (int j4 = 0; j4 < 8; j4++) {
          float4 pv = p4[j4];
          ax = fmaf(pv.x, vr[j4 * 4],     ax);
          ay = fmaf(pv.y, vr[j4 * 4 + 1], ay);
          az = fmaf(pv.z, vr[j4 * 4 + 2], az);
          aw = fmaf(pv.w, vr[j4 * 4 + 3], aw);
        }
        o[r] = (ax + ay) + (az + aw);
      }
    }
    __syncthreads();
    if (tile < 15) {
      STAGE_WRITE();
      #pragma unroll
      for (int r = 0; r < RW; r++) pb_cur[r] = pb_nxt[r];
    }
    __syncthreads();
  }
  #pragma unroll
  for (int r = 0; r < RW; r++) {
    float ov = o[r] + __shfl_xor(o[r], 32);
    if (lane < 32) wt[(q0 + w * RW + r) * C + h * 32 + lane] = ov / lrun[r];
  }
#undef STAGE_LOAD
#undef STAGE_WRITE
}

// ---------------- K4: output GEMM + residual + LayerNorm ----------------
__global__ __launch_bounds__(384) void k_out(
    const float* __restrict__ wt, const float* __restrict__ Wo,
    const float* __restrict__ bo, const float* __restrict__ single,
    const float* __restrict__ gamma, const float* __restrict__ beta,
    float* __restrict__ out)
{
  __shared__ __align__(16) float wt_s[4 * C];
  __shared__ __align__(16) float red[4][2][6];
  int t = threadIdx.x, n0 = blockIdx.x * 4;
  for (int idx = t; idx < 4 * C; idx += 384) wt_s[idx] = wt[n0 * C + idx];
  __syncthreads();
  float acc[4] = {};
  for (int ck = 0; ck < C; ck++) {
    float w = Wo[ck * C + t];
    #pragma unroll
    for (int i = 0; i < 4; i++) acc[i] = fmaf(wt_s[i * C + ck], w, acc[i]);
  }
  float x[4], bov = bo[t];
  #pragma unroll
  for (int i = 0; i < 4; i++) x[i] = single[(n0 + i) * C + t] + acc[i] + bov;
  int wid = t >> 6, lane = t & 63;
  #pragma unroll
  for (int i = 0; i < 4; i++) {
    float s = x[i], s2 = x[i] * x[i];
    #pragma unroll
    for (int off = 32; off; off >>= 1) { s += __shfl_xor(s, off); s2 += __shfl_xor(s2, off); }
    if (lane == 0) { red[i][0][wid] = s; red[i][1][wid] = s2; }
  }
  __syncthreads();
  float gv = gamma[t], bv = beta[t];
  #pragma unroll
  for (int i = 0; i < 4; i++) {
    float S = 0.f, S2 = 0.f;
    #pragma unroll
    for (int w = 0; w < 6; w++) { S += red[i][0][w]; S2 += red[i][1][w]; }
    float mu = S * (1.0f / C);
    float var = S2 * (1.0f / C) - mu * mu;
    out[(n0 + i) * C + t] = (x[i] - mu) * rsqrtf(var + LN_EPS) * gv + bv;
  }
}

extern "C" void kernel_launch(void* const* d_in, const int* in_sizes, int n_in,
                              void* d_out, int out_size, void* d_ws, size_t ws_size,
                              hipStream_t stream) {
  const float* single = (const float*)d_in[0];
  const float* pair   = (const float*)d_in[1];
  const float* rot    = (const float*)d_in[2];
  const float* Wq  = (const float*)d_in[4];  const float* bq  = (const float*)d_in[5];
  const float* Wk  = (const float*)d_in[6];  const float* bk  = (const float*)d_in[7];
  const float* Wv  = (const float*)d_in[8];  const float* bv  = (const float*)d_in[9];
  const float* Wp  = (const float*)d_in[10]; const float* bp  = (const float*)d_in[11];
  const float* Wpq = (const float*)d_in[12]; const float* bpq = (const float*)d_in[13];
  const float* Wpk = (const float*)d_in[14]; const float* bpk = (const float*)d_in[15];
  const float* Wo  = (const float*)d_in[16]; const float* bo  = (const float*)d_in[17];
  const float* gamma = (const float*)d_in[18]; const float* beta = (const float*)d_in[19];

  float* ws  = (float*)d_ws;
  float* pb  = ws;                           // [12][1024*1024]
  float* q   = pb + 12L * N * N;             // [N][C]
  float* kT  = q   + N * C;                  // [C][N]
  float* v   = kT  + N * C;                  // [N][C]
  float* qp  = v   + N * C;                  // [N][144]
  float* kp  = qp  + N * HP;                 // [N][144]
  float* qg  = kp  + N * HP;                 // [N][144]
  float* kgT = qg  + N * HP;                 // [144][N]
  float* sq  = kgT + N * HP;                 // [N][12]
  float* skT = sq  + N * H;                  // [12][N]
  float* wt  = skT + N * H;                  // [N][C]

  k_qkv<<<dim3(30, 16), 256, 0, stream>>>(single, Wq, bq, Wk, bk, Wv, bv,
                                          Wpq, bpq, Wpk, bpk, q, kT, v, qp, kp);
  k_rot<<<N, 256, 0, stream>>>(qp, kp, rot, qg, kgT, sq, skT);
  k_pb<<<4096, 256, 0, stream>>>((const float4*)pair, Wp, bp, pb);
  k_attn<<<384, 256, 0, stream>>>(q, kT, v, qg, kgT, sq, skT, pb, wt);
  k_out<<<256, 384, 0, stream>>>(wt, Wo, bo, single, gamma, beta, (float*)d_out);
}

// Round 5
// 376.941 us; speedup vs baseline: 1.7146x; 1.1818x over previous
//
#include <hip/hip_runtime.h>
#include <math.h>

#define N 1024
#define C 384
#define H 12
#define CH 32
#define DP 128
#define HP 144
#define MT 64   // m-tile (keys per tile)
#define RW 4    // q-rows per wave
#define QBL 16  // q-rows per block
#define SCALING 0.17677669529663687f
#define LN_EPS 1e-5f

// ---------------- K1: fused projections GEMM ----------------
__global__ __launch_bounds__(256) void k_qkv(
    const float* __restrict__ single,
    const float* __restrict__ Wq, const float* __restrict__ bq,
    const float* __restrict__ Wk, const float* __restrict__ bk,
    const float* __restrict__ Wv, const float* __restrict__ bv,
    const float* __restrict__ Wpq, const float* __restrict__ bpq,
    const float* __restrict__ Wpk, const float* __restrict__ bpk,
    float* __restrict__ q, float* __restrict__ kT, float* __restrict__ v,
    float* __restrict__ qp, float* __restrict__ kp)
{
  __shared__ __align__(16) float A_s[64 * 33];
  __shared__ __align__(16) float B_s[32 * 48];
  int t = threadIdx.x;
  int nt = blockIdx.x, mt = blockIdx.y;
  int m0 = mt * 64;
  const float* W; const float* bias; int ld, kind, cb;
  if (nt < 8)       { W = Wq;  bias = bq;  ld = C;  cb = nt * 48;        kind = 0; }
  else if (nt < 16) { W = Wk;  bias = bk;  ld = C;  cb = (nt - 8) * 48;  kind = 1; }
  else if (nt < 24) { W = Wv;  bias = bv;  ld = C;  cb = (nt - 16) * 48; kind = 2; }
  else if (nt < 27) { W = Wpq; bias = bpq; ld = HP; cb = (nt - 24) * 48; kind = 3; }
  else              { W = Wpk; bias = bpk; ld = HP; cb = (nt - 27) * 48; kind = 4; }
  int tr = t >> 4, tc = t & 15;
  float acc[4][3] = {};
  for (int k0 = 0; k0 < C; k0 += 32) {
    if (k0) __syncthreads();
    #pragma unroll
    for (int i = 0; i < 8; i++) {
      int fi = i * 256 + t; int row = fi >> 5, col = fi & 31;
      A_s[row * 33 + col] = single[(m0 + row) * C + k0 + col];
    }
    #pragma unroll
    for (int i = 0; i < 6; i++) {
      int fi = i * 256 + t; int row = fi / 48, col = fi % 48;
      B_s[row * 48 + col] = W[(k0 + row) * ld + cb + col];
    }
    __syncthreads();
    #pragma unroll
    for (int k = 0; k < 32; k++) {
      float a[4], b[3];
      #pragma unroll
      for (int r = 0; r < 4; r++) a[r] = A_s[(tr * 4 + r) * 33 + k];
      #pragma unroll
      for (int c = 0; c < 3; c++) b[c] = B_s[k * 48 + tc * 3 + c];
      #pragma unroll
      for (int r = 0; r < 4; r++)
        #pragma unroll
        for (int c = 0; c < 3; c++) acc[r][c] = fmaf(a[r], b[c], acc[r][c]);
    }
  }
  #pragma unroll
  for (int c = 0; c < 3; c++) {
    int col = cb + tc * 3 + c;
    float bb = bias[col];
    #pragma unroll
    for (int r = 0; r < 4; r++) {
      int row = m0 + tr * 4 + r;
      float val = acc[r][c] + bb;
      if (kind == 0)      q[row * C + col] = val;
      else if (kind == 1) kT[col * N + row] = val;
      else if (kind == 2) v[row * C + col] = val;
      else if (kind == 3) qp[row * HP + col] = val;
      else                kp[row * HP + col] = val;
    }
  }
}

// ---------------- K1b: rotate points, sq/sk sums ----------------
__global__ __launch_bounds__(256) void k_rot(
    const float* __restrict__ qp, const float* __restrict__ kp,
    const float* __restrict__ rot,
    float* __restrict__ qg, float* __restrict__ kgT,
    float* __restrict__ sq, float* __restrict__ skT)
{
  __shared__ __align__(16) float qp_s[HP], kp_s[HP], rot_s[9], q2_s[HP], k2_s[HP];
  int n = blockIdx.x, t = threadIdx.x;
  if (t < HP) { qp_s[t] = qp[n * HP + t]; kp_s[t] = kp[n * HP + t]; }
  if (t < 9)  rot_s[t] = rot[n * 9 + t];
  __syncthreads();
  if (t < HP) {
    int h = t / 12, r12 = t % 12, y = r12 >> 2, p = r12 & 3;
    float qgv = rot_s[y*3] * qp_s[h*12 + p] + rot_s[y*3+1] * qp_s[h*12 + 4 + p]
              + rot_s[y*3+2] * qp_s[h*12 + 8 + p];
    float kgv = rot_s[y*3] * kp_s[h*12 + p] + rot_s[y*3+1] * kp_s[h*12 + 4 + p]
              + rot_s[y*3+2] * kp_s[h*12 + 8 + p];
    qg[n * HP + t] = qgv; kgT[t * N + n] = kgv;
    q2_s[t] = qgv * qgv; k2_s[t] = kgv * kgv;
  }
  __syncthreads();
  if (t < H) {
    float s1 = 0.f, s2 = 0.f;
    #pragma unroll
    for (int e = 0; e < 12; e++) { s1 += q2_s[t * 12 + e]; s2 += k2_s[t * 12 + e]; }
    sq[n * H + t] = s1; skT[t * N + n] = s2;
  }
}

// ---------------- K2: pair bias GEMM [N*N,128] @ [128,12] ----------------
// 4 threads per row: each 4-lane group reads 64 contiguous bytes per
// instruction -> 16 fully-consumed 64B lines/instr (line-perfect
// coalescing). shfl_xor(1,2) reduce across the 4 lanes; outputs
// transposed via 3KB LDS so stores are 64-float coalesced runs per head.
__global__ __launch_bounds__(256) void k_pb(
    const float4* __restrict__ pair4, const float* __restrict__ Wp,
    const float* __restrict__ bp, float* __restrict__ pb)
{
  __shared__ __align__(16) float wp_s[12 * 128];   // [h][d]
  __shared__ __align__(16) float ob_s[12][64];
  int t = threadIdx.x;
  #pragma unroll
  for (int i = 0; i < 6; i++) {
    int fi = i * 256 + t; int h = fi >> 7, d = fi & 127;
    wp_s[h * 128 + d] = Wp[d * 12 + h];
  }
  __syncthreads();
  int tc = t & 3, rid = t >> 2;                    // 64 rows per block
  long row = (long)blockIdx.x * 64 + rid;
  const float4* rp = pair4 + row * 32;
  const float4* w4 = (const float4*)wp_s;          // [h][32]
  float acc[12] = {};
  #pragma unroll
  for (int i = 0; i < 8; i++) {
    float4 a = rp[i * 4 + tc];
    #pragma unroll
    for (int h = 0; h < 12; h++) {
      float4 w = w4[h * 32 + i * 4 + tc];
      acc[h] = fmaf(a.x, w.x, acc[h]);
      acc[h] = fmaf(a.y, w.y, acc[h]);
      acc[h] = fmaf(a.z, w.z, acc[h]);
      acc[h] = fmaf(a.w, w.w, acc[h]);
    }
  }
  #pragma unroll
  for (int h = 0; h < 12; h++) {
    acc[h] += __shfl_xor(acc[h], 1);
    acc[h] += __shfl_xor(acc[h], 2);
  }
  if (tc == 0) {
    #pragma unroll
    for (int h = 0; h < 12; h++) ob_s[h][rid] = acc[h] + bp[h];
  }
  __syncthreads();
  long b0 = (long)blockIdx.x * 64;
  #pragma unroll
  for (int i = 0; i < 3; i++) {
    int idx = i * 256 + t; int h = idx >> 6, r = idx & 63;
    pb[(long)h * (N * (long)N) + b0 + r] = ob_s[h][r];
  }
}

// ---------------- K3: flash attention v4 ----------------
// QBL=16, RW=4 -> grid 768 = exactly 3 blocks/CU (balanced). Double-buffered
// k/v/kg LDS tiles -> ONE barrier per tile; reg-prefetch of tile+1 stage and
// pb rows overlaps HBM/L2 latency with compute. XCD swizzle: 1.5 heads/XCD.
__global__ __launch_bounds__(256) void k_attn(
    const float* __restrict__ q, const float* __restrict__ kT,
    const float* __restrict__ v, const float* __restrict__ qg,
    const float* __restrict__ kgT, const float* __restrict__ sq,
    const float* __restrict__ skT, const float* __restrict__ pb,
    float* __restrict__ wt)
{
  __shared__ __align__(16) float k_s[2][32][MT];
  __shared__ __align__(16) float v_s[2][MT][32];
  __shared__ __align__(16) float kg_s[2][12][MT];
  __shared__ __align__(16) float q_s[QBL][32];
  __shared__ __align__(16) float qg_s[QBL][12];
  __shared__ __align__(16) float sq_s[QBL];
  __shared__ __align__(16) float p_s[4][RW][MT];

  int t = threadIdx.x;
  int bid = blockIdx.x;
  int s = (bid & 7) * 96 + (bid >> 3);   // XCD x -> s in [96x,96x+96): 1.5 heads
  int h = s >> 6, qb = s & 63;
  int q0 = qb * QBL;
  int w = t >> 6, lane = t & 63;
  long pbbase = (long)h * (N * (long)N);

  if (t < QBL * 8) {
    int r = t >> 3, c4 = t & 7;
    *(float4*)&q_s[r][c4 * 4] = *(const float4*)&q[(q0 + r) * C + h * 32 + c4 * 4];
  }
  if (t < QBL * 3) {
    int r = t / 3, e4 = t % 3;
    *(float4*)&qg_s[r][e4 * 4] = *(const float4*)&qg[(q0 + r) * HP + h * 12 + e4 * 4];
  }
  if (t < QBL) sq_s[t] = sq[(q0 + t) * H + h];

  int c0 = t >> 4, m4 = t & 15;          // k/kg job coords
  int mr0 = t >> 3, c4v = t & 7;         // v job coords
  float4 pre[5];
  float pb_cur[RW], pb_nxt[RW];

#define STAGE_LOAD(M0) \
  { pre[0] = *(const float4*)&kT[(h * 32 + c0) * N + (M0) + m4 * 4]; \
    pre[1] = *(const float4*)&kT[(h * 32 + 16 + c0) * N + (M0) + m4 * 4]; \
    pre[2] = *(const float4*)&v[((M0) + mr0) * C + h * 32 + c4v * 4]; \
    pre[3] = *(const float4*)&v[((M0) + mr0 + 32) * C + h * 32 + c4v * 4]; \
    if (t < 192) pre[4] = *(const float4*)&kgT[(h * 12 + c0) * N + (M0) + m4 * 4]; }

#define STAGE_WRITE(B) \
  { *(float4*)&k_s[B][c0][m4 * 4] = pre[0]; \
    *(float4*)&k_s[B][16 + c0][m4 * 4] = pre[1]; \
    *(float4*)&v_s[B][mr0][c4v * 4] = pre[2]; \
    *(float4*)&v_s[B][mr0 + 32][c4v * 4] = pre[3]; \
    if (t < 192) *(float4*)&kg_s[B][c0][m4 * 4] = pre[4]; }

  STAGE_LOAD(0);
  #pragma unroll
  for (int r = 0; r < RW; r++)
    pb_cur[r] = pb[pbbase + (long)(q0 + w * RW + r) * N + lane];
  STAGE_WRITE(0);
  __syncthreads();

  float mrun[RW], lrun[RW] = {}, o[RW] = {};
  #pragma unroll
  for (int r = 0; r < RW; r++) mrun[r] = -INFINITY;

  for (int tile = 0; tile < 16; tile++) {
    int m0 = tile * MT;
    int cb = tile & 1;
    if (tile < 15) {
      STAGE_LOAD(m0 + MT);
      #pragma unroll
      for (int r = 0; r < RW; r++)
        pb_nxt[r] = pb[pbbase + (long)(q0 + w * RW + r) * N + m0 + MT + lane];
    }
    // ---- QK^T + point logits + online softmax (lanes = m) ----
    float kr[32], kgr[12];
    #pragma unroll
    for (int c = 0; c < 32; c++) kr[c] = k_s[cb][c][lane];
    #pragma unroll
    for (int e = 0; e < 12; e++) kgr[e] = kg_s[cb][e][lane];
    float skv = skT[h * N + m0 + lane];
    float sc[RW];
    #pragma unroll
    for (int r = 0; r < RW; r++) {
      int row = w * RW + r;
      float a0 = 0.f, a1 = 0.f, a2 = 0.f, a3 = 0.f;
      const float4* q4p = (const float4*)q_s[row];
      #pragma unroll
      for (int c4 = 0; c4 < 8; c4++) {
        float4 qv = q4p[c4];
        a0 = fmaf(qv.x, kr[c4 * 4],     a0);
        a1 = fmaf(qv.y, kr[c4 * 4 + 1], a1);
        a2 = fmaf(qv.z, kr[c4 * 4 + 2], a2);
        a3 = fmaf(qv.w, kr[c4 * 4 + 3], a3);
      }
      float b0 = 0.f, b1 = 0.f, b2 = 0.f, b3 = 0.f;
      const float4* qg4p = (const float4*)qg_s[row];
      #pragma unroll
      for (int e4 = 0; e4 < 3; e4++) {
        float4 qv = qg4p[e4];
        b0 = fmaf(qv.x, kgr[e4 * 4],     b0);
        b1 = fmaf(qv.y, kgr[e4 * 4 + 1], b1);
        b2 = fmaf(qv.z, kgr[e4 * 4 + 2], b2);
        b3 = fmaf(qv.w, kgr[e4 * 4 + 3], b3);
      }
      float Lq = (a0 + a1) + (a2 + a3);
      float Lp = (b0 + b1) + (b2 + b3);
      float L = Lq * SCALING + pb_cur[r]
              - 0.5f * SCALING * (sq_s[row] + skv - 2.0f * Lp);
      float tmax = L;
      #pragma unroll
      for (int off = 32; off; off >>= 1) tmax = fmaxf(tmax, __shfl_xor(tmax, off));
      float mnew = fmaxf(mrun[r], tmax);
      float p = __expf(L - mnew);
      float ts = p;
      #pragma unroll
      for (int off = 32; off; off >>= 1) ts += __shfl_xor(ts, off);
      sc[r] = __expf(mrun[r] - mnew);
      lrun[r] = lrun[r] * sc[r] + ts;
      mrun[r] = mnew;
      p_s[w][r][lane] = p;   // wave-private row
    }
    // ---- AV (lanes = (c, m-half)) ----
    {
      int cc = lane & 31, seg = lane >> 5;
      float vr[32];
      #pragma unroll
      for (int jj = 0; jj < 32; jj++) vr[jj] = v_s[cb][seg * 32 + jj][cc];
      #pragma unroll
      for (int r = 0; r < RW; r++) {
        float ax = o[r] * sc[r], ay = 0.f, az = 0.f, aw = 0.f;
        const float4* p4 = (const float4*)&p_s[w][r][seg * 32];
        #pragma unroll
        for (int j4 = 0; j4 < 8; j4++) {
          float4 pv = p4[j4];
          ax = fmaf(pv.x, vr[j4 * 4],     ax);
          ay = fmaf(pv.y, vr[j4 * 4 + 1], ay);
          az = fmaf(pv.z, vr[j4 * 4 + 2], az);
          aw = fmaf(pv.w, vr[j4 * 4 + 3], aw);
        }
        o[r] = (ax + ay) + (az + aw);
      }
    }
    if (tile < 15) {
      STAGE_WRITE(cb ^ 1);
      #pragma unroll
      for (int r = 0; r < RW; r++) pb_cur[r] = pb_nxt[r];
    }
    __syncthreads();
  }
  #pragma unroll
  for (int r = 0; r < RW; r++) {
    float ov = o[r] + __shfl_xor(o[r], 32);
    if (lane < 32) wt[(q0 + w * RW + r) * C + h * 32 + lane] = ov / lrun[r];
  }
#undef STAGE_LOAD
#undef STAGE_WRITE
}

// ---------------- K4: output GEMM + residual + LayerNorm ----------------
__global__ __launch_bounds__(384) void k_out(
    const float* __restrict__ wt, const float* __restrict__ Wo,
    const float* __restrict__ bo, const float* __restrict__ single,
    const float* __restrict__ gamma, const float* __restrict__ beta,
    float* __restrict__ out)
{
  __shared__ __align__(16) float wt_s[4 * C];
  __shared__ __align__(16) float red[4][2][6];
  int t = threadIdx.x, n0 = blockIdx.x * 4;
  for (int idx = t; idx < 4 * C; idx += 384) wt_s[idx] = wt[n0 * C + idx];
  __syncthreads();
  float acc[4] = {};
  for (int ck = 0; ck < C; ck++) {
    float w = Wo[ck * C + t];
    #pragma unroll
    for (int i = 0; i < 4; i++) acc[i] = fmaf(wt_s[i * C + ck], w, acc[i]);
  }
  float x[4], bov = bo[t];
  #pragma unroll
  for (int i = 0; i < 4; i++) x[i] = single[(n0 + i) * C + t] + acc[i] + bov;
  int wid = t >> 6, lane = t & 63;
  #pragma unroll
  for (int i = 0; i < 4; i++) {
    float s = x[i], s2 = x[i] * x[i];
    #pragma unroll
    for (int off = 32; off; off >>= 1) { s += __shfl_xor(s, off); s2 += __shfl_xor(s2, off); }
    if (lane == 0) { red[i][0][wid] = s; red[i][1][wid] = s2; }
  }
  __syncthreads();
  float gv = gamma[t], bv = beta[t];
  #pragma unroll
  for (int i = 0; i < 4; i++) {
    float S = 0.f, S2 = 0.f;
    #pragma unroll
    for (int w = 0; w < 6; w++) { S += red[i][0][w]; S2 += red[i][1][w]; }
    float mu = S * (1.0f / C);
    float var = S2 * (1.0f / C) - mu * mu;
    out[(n0 + i) * C + t] = (x[i] - mu) * rsqrtf(var + LN_EPS) * gv + bv;
  }
}

extern "C" void kernel_launch(void* const* d_in, const int* in_sizes, int n_in,
                              void* d_out, int out_size, void* d_ws, size_t ws_size,
                              hipStream_t stream) {
  const float* single = (const float*)d_in[0];
  const float* pair   = (const float*)d_in[1];
  const float* rot    = (const float*)d_in[2];
  const float* Wq  = (const float*)d_in[4];  const float* bq  = (const float*)d_in[5];
  const float* Wk  = (const float*)d_in[6];  const float* bk  = (const float*)d_in[7];
  const float* Wv  = (const float*)d_in[8];  const float* bv  = (const float*)d_in[9];
  const float* Wp  = (const float*)d_in[10]; const float* bp  = (const float*)d_in[11];
  const float* Wpq = (const float*)d_in[12]; const float* bpq = (const float*)d_in[13];
  const float* Wpk = (const float*)d_in[14]; const float* bpk = (const float*)d_in[15];
  const float* Wo  = (const float*)d_in[16]; const float* bo  = (const float*)d_in[17];
  const float* gamma = (const float*)d_in[18]; const float* beta = (const float*)d_in[19];

  float* ws  = (float*)d_ws;
  float* pb  = ws;                           // [12][1024*1024]
  float* q   = pb + 12L * N * N;             // [N][C]
  float* kT  = q   + N * C;                  // [C][N]
  float* v   = kT  + N * C;                  // [N][C]
  float* qp  = v   + N * C;                  // [N][144]
  float* kp  = qp  + N * HP;                 // [N][144]
  float* qg  = kp  + N * HP;                 // [N][144]
  float* kgT = qg  + N * HP;                 // [144][N]
  float* sq  = kgT + N * HP;                 // [N][12]
  float* skT = sq  + N * H;                  // [12][N]
  float* wt  = skT + N * H;                  // [N][C]

  k_qkv<<<dim3(30, 16), 256, 0, stream>>>(single, Wq, bq, Wk, bk, Wv, bv,
                                          Wpq, bpq, Wpk, bpk, q, kT, v, qp, kp);
  k_rot<<<N, 256, 0, stream>>>(qp, kp, rot, qg, kgT, sq, skT);
  k_pb<<<16384, 256, 0, stream>>>((const float4*)pair, Wp, bp, pb);
  k_attn<<<768, 256, 0, stream>>>(q, kT, v, qg, kgT, sq, skT, pb, wt);
  k_out<<<256, 384, 0, stream>>>(wt, Wo, bo, single, gamma, beta, (float*)d_out);
}

// Round 6
// 328.995 us; speedup vs baseline: 1.9645x; 1.1457x over previous
//
#include <hip/hip_runtime.h>
#include <math.h>

#define N 1024
#define C 384
#define H 12
#define DP 128
#define HP 144
#define MT 64   // keys per tile
#define NT 16   // tiles
#define RW 4    // q-rows per wave
#define QBL 16  // q-rows per block
#define SCALING 0.17677669529663687f
#define LN_EPS 1e-5f

// ---------------- K1: fused projections GEMM ----------------
// Also materializes kc_g[h][n][48] = [k(32) | kg(12, filled by k_rot) | pad]
__global__ __launch_bounds__(256) void k_qkv(
    const float* __restrict__ single,
    const float* __restrict__ Wq, const float* __restrict__ bq,
    const float* __restrict__ Wk, const float* __restrict__ bk,
    const float* __restrict__ Wv, const float* __restrict__ bv,
    const float* __restrict__ Wpq, const float* __restrict__ bpq,
    const float* __restrict__ Wpk, const float* __restrict__ bpk,
    float* __restrict__ q, float* __restrict__ kcg, float* __restrict__ v,
    float* __restrict__ qp, float* __restrict__ kp)
{
  __shared__ __align__(16) float A_s[64 * 33];
  __shared__ __align__(16) float B_s[32 * 48];
  int t = threadIdx.x;
  int nt = blockIdx.x, mt = blockIdx.y;
  int m0 = mt * 64;
  const float* W; const float* bias; int ld, kind, cb;
  if (nt < 8)       { W = Wq;  bias = bq;  ld = C;  cb = nt * 48;        kind = 0; }
  else if (nt < 16) { W = Wk;  bias = bk;  ld = C;  cb = (nt - 8) * 48;  kind = 1; }
  else if (nt < 24) { W = Wv;  bias = bv;  ld = C;  cb = (nt - 16) * 48; kind = 2; }
  else if (nt < 27) { W = Wpq; bias = bpq; ld = HP; cb = (nt - 24) * 48; kind = 3; }
  else              { W = Wpk; bias = bpk; ld = HP; cb = (nt - 27) * 48; kind = 4; }
  int tr = t >> 4, tc = t & 15;
  float acc[4][3] = {};
  for (int k0 = 0; k0 < C; k0 += 32) {
    if (k0) __syncthreads();
    #pragma unroll
    for (int i = 0; i < 8; i++) {
      int fi = i * 256 + t; int row = fi >> 5, col = fi & 31;
      A_s[row * 33 + col] = single[(m0 + row) * C + k0 + col];
    }
    #pragma unroll
    for (int i = 0; i < 6; i++) {
      int fi = i * 256 + t; int row = fi / 48, col = fi % 48;
      B_s[row * 48 + col] = W[(k0 + row) * ld + cb + col];
    }
    __syncthreads();
    #pragma unroll
    for (int k = 0; k < 32; k++) {
      float a[4], b[3];
      #pragma unroll
      for (int r = 0; r < 4; r++) a[r] = A_s[(tr * 4 + r) * 33 + k];
      #pragma unroll
      for (int c = 0; c < 3; c++) b[c] = B_s[k * 48 + tc * 3 + c];
      #pragma unroll
      for (int r = 0; r < 4; r++)
        #pragma unroll
        for (int c = 0; c < 3; c++) acc[r][c] = fmaf(a[r], b[c], acc[r][c]);
    }
  }
  #pragma unroll
  for (int c = 0; c < 3; c++) {
    int col = cb + tc * 3 + c;
    float bb = bias[col];
    #pragma unroll
    for (int r = 0; r < 4; r++) {
      int row = m0 + tr * 4 + r;
      float val = acc[r][c] + bb;
      if (kind == 0)      q[row * C + col] = val;
      else if (kind == 1) kcg[((col >> 5) * N + row) * 48 + (col & 31)] = val;
      else if (kind == 2) v[row * C + col] = val;
      else if (kind == 3) qp[row * HP + col] = val;
      else                kp[row * HP + col] = val;
    }
  }
}

// ---------------- K1b: rotate points, sq/sk sums, finish kc ----------------
__global__ __launch_bounds__(256) void k_rot(
    const float* __restrict__ qp, const float* __restrict__ kp,
    const float* __restrict__ rot,
    float* __restrict__ qg, float* __restrict__ kcg,
    float* __restrict__ sq, float* __restrict__ sknh)
{
  __shared__ __align__(16) float qp_s[HP], kp_s[HP], rot_s[9], q2_s[HP], k2_s[HP];
  int n = blockIdx.x, t = threadIdx.x;
  if (t < HP) { qp_s[t] = qp[n * HP + t]; kp_s[t] = kp[n * HP + t]; }
  if (t < 9)  rot_s[t] = rot[n * 9 + t];
  __syncthreads();
  if (t < HP) {
    int h = t / 12, r12 = t % 12, y = r12 >> 2, p = r12 & 3;
    float qgv = rot_s[y*3] * qp_s[h*12 + p] + rot_s[y*3+1] * qp_s[h*12 + 4 + p]
              + rot_s[y*3+2] * qp_s[h*12 + 8 + p];
    float kgv = rot_s[y*3] * kp_s[h*12 + p] + rot_s[y*3+1] * kp_s[h*12 + 4 + p]
              + rot_s[y*3+2] * kp_s[h*12 + 8 + p];
    qg[n * HP + t] = qgv;
    kcg[(h * N + n) * 48 + 32 + r12] = kgv;
    q2_s[t] = qgv * qgv; k2_s[t] = kgv * kgv;
  }
  if (t < 48) kcg[((t >> 2) * N + n) * 48 + 44 + (t & 3)] = 0.f;  // zero pad
  __syncthreads();
  if (t < H) {
    float s1 = 0.f, s2 = 0.f;
    #pragma unroll
    for (int e = 0; e < 12; e++) { s1 += q2_s[t * 12 + e]; s2 += k2_s[t * 12 + e]; }
    sq[n * H + t] = s1; sknh[n * H + t] = s2;
  }
}

// ---------------- K2: pair bias GEMM + rank-1 fold ----------------
// pb'[h][n][m] = pair.Wp + bp - 0.5*S*(sq[n][h] + sk[m][h])
__global__ __launch_bounds__(256) void k_pb(
    const float4* __restrict__ pair4, const float* __restrict__ Wp,
    const float* __restrict__ bp, const float* __restrict__ sq,
    const float* __restrict__ sknh, float* __restrict__ pb)
{
  __shared__ __align__(16) float wp_s[12 * 128];   // [h][d]
  __shared__ __align__(16) float ob_s[12][64];
  __shared__ float sq_s[12], bp_s[12];
  int t = threadIdx.x;
  int bid = blockIdx.x;
  int n = bid >> 4;                 // 16 blocks of 64 m per n-row
  int m0 = (bid & 15) * 64;
  #pragma unroll
  for (int i = 0; i < 6; i++) {
    int fi = i * 256 + t; int h = fi >> 7, d = fi & 127;
    wp_s[h * 128 + d] = Wp[d * 12 + h];
  }
  if (t < 12) { sq_s[t] = sq[n * 12 + t]; bp_s[t] = bp[t]; }
  __syncthreads();
  int tc = t & 3, rid = t >> 2;                    // 64 rows per block
  long row = (long)n * N + m0 + rid;
  const float4* rp = pair4 + row * 32;
  const float4* w4 = (const float4*)wp_s;          // [h][32]
  float acc[12] = {};
  #pragma unroll
  for (int i = 0; i < 8; i++) {
    float4 a = rp[i * 4 + tc];
    #pragma unroll
    for (int h = 0; h < 12; h++) {
      float4 w = w4[h * 32 + i * 4 + tc];
      acc[h] = fmaf(a.x, w.x, acc[h]);
      acc[h] = fmaf(a.y, w.y, acc[h]);
      acc[h] = fmaf(a.z, w.z, acc[h]);
      acc[h] = fmaf(a.w, w.w, acc[h]);
    }
  }
  #pragma unroll
  for (int h = 0; h < 12; h++) {
    acc[h] += __shfl_xor(acc[h], 1);
    acc[h] += __shfl_xor(acc[h], 2);
  }
  if (tc == 0) {
    float skr[12];
    #pragma unroll
    for (int i = 0; i < 3; i++)
      *(float4*)&skr[i * 4] = *(const float4*)&sknh[(m0 + rid) * 12 + i * 4];
    #pragma unroll
    for (int h = 0; h < 12; h++)
      ob_s[h][rid] = acc[h] + bp_s[h] - 0.5f * SCALING * (sq_s[h] + skr[h]);
  }
  __syncthreads();
  long b0 = (long)bid * 64;
  #pragma unroll
  for (int i = 0; i < 3; i++) {
    int idx = i * 256 + t; int h = idx >> 6, r = idx & 63;
    pb[(long)h * (N * (long)N) + b0 + r] = ob_s[h][r];
  }
}

// ---------------- K3: flash attention v6 (DS-op minimized) ----------------
// Unified 48-dim kc rows (XOR-swz b128), prescaled qc broadcast, pb' carries
// all rank-1 terms, per-lane deferred lsum (no sum shfl), transposed swz v.
__global__ __launch_bounds__(256) void k_attn(
    const float* __restrict__ q, const float* __restrict__ qg,
    const float* __restrict__ kcg, const float* __restrict__ v,
    const float* __restrict__ pb, float* __restrict__ wt)
{
  __shared__ __align__(16) float kc_s[64 * 64];    // [m][16 chunks], XOR (m&7)
  __shared__ __align__(16) float v_s[32 * 64];     // [c][m], XOR (c&7)
  __shared__ __align__(16) float qc_s[QBL][48];    // S-prescaled [q|qg|0]
  __shared__ __align__(16) float p_s[4][RW][MT];

  int t = threadIdx.x;
  int bid = blockIdx.x;
  int s = (bid & 7) * 96 + (bid >> 3);   // 1.5 heads per XCD
  int h = s >> 6, qb = s & 63;
  int q0 = qb * QBL;
  int w = t >> 6, lane = t & 63;
  long pbbase = (long)h * (N * (long)N);
  const float* kch = kcg + (long)h * N * 48;
  int hc32 = h * 32;
  int mr = t >> 3, cq = t & 7;

  float4 pk0, pk1, pk2, pv0, pv1;
  float pb_cur[RW], pb_nxt[RW];

#define STAGE_LOAD(M0) \
  { int f0 = t, f1 = 256 + t, f2 = 512 + t; \
    pk0 = *(const float4*)&kch[((M0) + f0 / 12) * 48 + (f0 % 12) * 4]; \
    pk1 = *(const float4*)&kch[((M0) + f1 / 12) * 48 + (f1 % 12) * 4]; \
    pk2 = *(const float4*)&kch[((M0) + f2 / 12) * 48 + (f2 % 12) * 4]; \
    pv0 = *(const float4*)&v[((M0) + mr) * C + hc32 + cq * 4]; \
    pv1 = *(const float4*)&v[((M0) + 32 + mr) * C + hc32 + cq * 4]; }

#define ST_KC(F, VAL) \
  { int row_ = (F) / 12, c4_ = (F) % 12; \
    *(float4*)&kc_s[row_ * 64 + ((c4_ ^ (row_ & 7)) << 2)] = VAL; }
#define ST_V1(MM, CC, VV) \
  v_s[(CC) * 64 + ((((MM) >> 2) ^ ((CC) & 7)) << 2) + ((MM) & 3)] = VV;
#define ST_V(MM, VAL) \
  { ST_V1(MM, cq * 4 + 0, VAL.x) ST_V1(MM, cq * 4 + 1, VAL.y) \
    ST_V1(MM, cq * 4 + 2, VAL.z) ST_V1(MM, cq * 4 + 3, VAL.w) }

#define STAGE_WRITE() \
  { ST_KC(t, pk0) ST_KC(256 + t, pk1) ST_KC(512 + t, pk2) \
    ST_V(mr, pv0) ST_V(32 + mr, pv1) }

  // prologue: stage tile 0, build qc, load pb row chunk 0
  STAGE_LOAD(0);
  #pragma unroll
  for (int r = 0; r < RW; r++)
    pb_cur[r] = pb[pbbase + (long)(q0 + w * RW + r) * N + lane];
  if (t < QBL * 12) {
    int r = t / 12, c4 = t % 12;
    float4 val;
    if (c4 < 8)       val = *(const float4*)&q[(q0 + r) * C + hc32 + c4 * 4];
    else if (c4 < 11) val = *(const float4*)&qg[(q0 + r) * HP + h * 12 + (c4 - 8) * 4];
    else              val = make_float4(0.f, 0.f, 0.f, 0.f);
    val.x *= SCALING; val.y *= SCALING; val.z *= SCALING; val.w *= SCALING;
    *(float4*)&qc_s[r][c4 * 4] = val;
  }
  STAGE_WRITE();
  __syncthreads();

  float mrun[RW], lsum[RW] = {}, o[RW] = {};
  #pragma unroll
  for (int r = 0; r < RW; r++) mrun[r] = -INFINITY;
  int cc = lane & 31, seg = lane >> 5;

  for (int tile = 0; tile < NT; tile++) {
    int m0 = tile * MT;
    if (tile < NT - 1) {
      STAGE_LOAD(m0 + MT);
      #pragma unroll
      for (int r = 0; r < RW; r++)
        pb_nxt[r] = pb[pbbase + (long)(q0 + w * RW + r) * N + m0 + MT + lane];
    }
    // ---- QK (lanes = m): 11 swizzled b128 + 44 fma per row ----
    float L[RW];
    #pragma unroll
    for (int r = 0; r < RW; r++) L[r] = pb_cur[r];
    #pragma unroll
    for (int c4 = 0; c4 < 11; c4++) {
      float4 kv = *(const float4*)&kc_s[lane * 64 + ((c4 ^ (lane & 7)) << 2)];
      #pragma unroll
      for (int r = 0; r < RW; r++) {
        float4 qv = *(const float4*)&qc_s[w * RW + r][c4 * 4];
        L[r] = fmaf(qv.x, kv.x, L[r]);
        L[r] = fmaf(qv.y, kv.y, L[r]);
        L[r] = fmaf(qv.z, kv.z, L[r]);
        L[r] = fmaf(qv.w, kv.w, L[r]);
      }
    }
    // ---- online softmax: max-reduce only; lsum is per-lane (deferred) ----
    float sc[RW];
    #pragma unroll
    for (int r = 0; r < RW; r++) {
      float tmax = L[r];
      #pragma unroll
      for (int off = 32; off; off >>= 1) tmax = fmaxf(tmax, __shfl_xor(tmax, off));
      float mnew = fmaxf(mrun[r], tmax);
      float p = __expf(L[r] - mnew);
      sc[r] = __expf(mrun[r] - mnew);
      lsum[r] = lsum[r] * sc[r] + p;
      mrun[r] = mnew;
      p_s[w][r][lane] = p;          // wave-private row
    }
    // ---- AV (lanes = (c, seg)): 8 swizzled b128 + 32 broadcast b128 ----
    #pragma unroll
    for (int r = 0; r < RW; r++) o[r] *= sc[r];
    #pragma unroll
    for (int j4 = 0; j4 < 8; j4++) {
      float4 vv = *(const float4*)&v_s[cc * 64 + (((seg * 8 + j4) ^ (cc & 7)) << 2)];
      #pragma unroll
      for (int r = 0; r < RW; r++) {
        float4 pv = *(const float4*)&p_s[w][r][seg * 32 + j4 * 4];
        o[r] = fmaf(pv.x, vv.x, o[r]);
        o[r] = fmaf(pv.y, vv.y, o[r]);
        o[r] = fmaf(pv.z, vv.z, o[r]);
        o[r] = fmaf(pv.w, vv.w, o[r]);
      }
    }
    __syncthreads();                 // all reads of kc_s/v_s done
    if (tile < NT - 1) {
      STAGE_WRITE();
      #pragma unroll
      for (int r = 0; r < RW; r++) pb_cur[r] = pb_nxt[r];
    }
    __syncthreads();                 // writes visible for next tile
  }
  #pragma unroll
  for (int r = 0; r < RW; r++) {
    float ls = lsum[r];
    #pragma unroll
    for (int off = 32; off; off >>= 1) ls += __shfl_xor(ls, off);
    float ov = o[r] + __shfl_xor(o[r], 32);
    if (lane < 32) wt[(q0 + w * RW + r) * C + hc32 + lane] = ov / ls;
  }
#undef STAGE_LOAD
#undef STAGE_WRITE
#undef ST_KC
#undef ST_V
#undef ST_V1
}

// ---------------- K4: output GEMM + residual + LayerNorm ----------------
__global__ __launch_bounds__(384) void k_out(
    const float* __restrict__ wt, const float* __restrict__ Wo,
    const float* __restrict__ bo, const float* __restrict__ single,
    const float* __restrict__ gamma, const float* __restrict__ beta,
    float* __restrict__ out)
{
  __shared__ __align__(16) float wt_s[4 * C];
  __shared__ __align__(16) float red[4][2][6];
  int t = threadIdx.x, n0 = blockIdx.x * 4;
  for (int idx = t; idx < 4 * C; idx += 384) wt_s[idx] = wt[n0 * C + idx];
  __syncthreads();
  float acc[4] = {};
  for (int ck = 0; ck < C; ck++) {
    float w = Wo[ck * C + t];
    #pragma unroll
    for (int i = 0; i < 4; i++) acc[i] = fmaf(wt_s[i * C + ck], w, acc[i]);
  }
  float x[4], bov = bo[t];
  #pragma unroll
  for (int i = 0; i < 4; i++) x[i] = single[(n0 + i) * C + t] + acc[i] + bov;
  int wid = t >> 6, lane = t & 63;
  #pragma unroll
  for (int i = 0; i < 4; i++) {
    float s = x[i], s2 = x[i] * x[i];
    #pragma unroll
    for (int off = 32; off; off >>= 1) { s += __shfl_xor(s, off); s2 += __shfl_xor(s2, off); }
    if (lane == 0) { red[i][0][wid] = s; red[i][1][wid] = s2; }
  }
  __syncthreads();
  float gv = gamma[t], bv = beta[t];
  #pragma unroll
  for (int i = 0; i < 4; i++) {
    float S = 0.f, S2 = 0.f;
    #pragma unroll
    for (int w = 0; w < 6; w++) { S += red[i][0][w]; S2 += red[i][1][w]; }
    float mu = S * (1.0f / C);
    float var = S2 * (1.0f / C) - mu * mu;
    out[(n0 + i) * C + t] = (x[i] - mu) * rsqrtf(var + LN_EPS) * gv + bv;
  }
}

extern "C" void kernel_launch(void* const* d_in, const int* in_sizes, int n_in,
                              void* d_out, int out_size, void* d_ws, size_t ws_size,
                              hipStream_t stream) {
  const float* single = (const float*)d_in[0];
  const float* pair   = (const float*)d_in[1];
  const float* rot    = (const float*)d_in[2];
  const float* Wq  = (const float*)d_in[4];  const float* bq  = (const float*)d_in[5];
  const float* Wk  = (const float*)d_in[6];  const float* bk  = (const float*)d_in[7];
  const float* Wv  = (const float*)d_in[8];  const float* bv  = (const float*)d_in[9];
  const float* Wp  = (const float*)d_in[10]; const float* bp  = (const float*)d_in[11];
  const float* Wpq = (const float*)d_in[12]; const float* bpq = (const float*)d_in[13];
  const float* Wpk = (const float*)d_in[14]; const float* bpk = (const float*)d_in[15];
  const float* Wo  = (const float*)d_in[16]; const float* bo  = (const float*)d_in[17];
  const float* gamma = (const float*)d_in[18]; const float* beta = (const float*)d_in[19];

  float* ws   = (float*)d_ws;
  float* pb   = ws;                          // [12][N*N]
  float* q    = pb + 12L * N * N;            // [N][C]
  float* v    = q + N * C;                   // [N][C]
  float* qp   = v + N * C;                   // [N][HP]
  float* kp   = qp + N * HP;                 // [N][HP]
  float* qg   = kp + N * HP;                 // [N][HP]
  float* kcg  = qg + N * HP;                 // [12][N][48]
  float* sq   = kcg + 12L * N * 48;          // [N][12]
  float* sknh = sq + N * H;                  // [N][12]
  float* wt   = sknh + N * H;                // [N][C]

  k_qkv<<<dim3(30, 16), 256, 0, stream>>>(single, Wq, bq, Wk, bk, Wv, bv,
                                          Wpq, bpq, Wpk, bpk, q, kcg, v, qp, kp);
  k_rot<<<N, 256, 0, stream>>>(qp, kp, rot, qg, kcg, sq, sknh);
  k_pb<<<16384, 256, 0, stream>>>((const float4*)pair, Wp, bp, sq, sknh, pb);
  k_attn<<<768, 256, 0, stream>>>(q, qg, kcg, v, pb, wt);
  k_out<<<256, 384, 0, stream>>>(wt, Wo, bo, single, gamma, beta, (float*)d_out);
}